// Round 5
// baseline (2167.369 us; speedup 1.0000x reference)
//
#include <hip/hip_runtime.h>

// Problem constants
#define IH 4096
#define IW 4096
#define KH 11
#define KW 11
#define OH (IH - KH + 1)   // 4086
#define OW (IW - KW + 1)   // 4086

// Tiling
#define BM 64              // output tile rows per block
#define BN 64              // output tile cols per block
#define TM 4               // outputs per thread (rows)
#define TN 4               // outputs per thread (cols)
#define TX 16              // threads in x
#define TY 16              // threads in y
#define LDS_H (BM + KH - 1)        // 74 input rows
#define LDS_W 84                   // row stride (floats); 76 data + 8 swizzle slack
#define NC4   19                   // float4 chunks per row (76 floats >= 74)
#define NCHUNK (LDS_H * NC4)       // 1406
#define NITER  ((NCHUNK + 255) / 256) // 6 staging iterations

// Bank-conflict swizzle. Within one wave the 4 ty-groups read rows r, r+4,
// r+8, r+12. addr mod 32 contributions: row*84 mod 32 = row*20 mod 32, plus
// FSWZ spreads {0,16,0,16} -> {0,16,8,24}: all four groups in distinct bank
// quadrants; only the free tx 2-way aliasing remains. FSWZ is a multiple of
// 8 floats (32 B) so 16B alignment is preserved; 76+8 <= 84 fits the stride.
#define FSWZ(row) ((((row) >> 3) & 1) * 8)

__global__ __launch_bounds__(256)   // NO min-waves hint: rounds 3/4 proved the
                                    // allocator meets caps by scratch-dumping.
void conv2d_f32_tile(const float* __restrict__ x,
                     const float* __restrict__ w,
                     const float* __restrict__ bias,
                     float* __restrict__ out) {
    __shared__ float tile[LDS_H * LDS_W];   // 74*84*4 = 24864 B

    const int tid = threadIdx.x;
    const int gx0 = blockIdx.x * BN;
    const int gy0 = blockIdx.y * BM;

    // ---- Stage 74x74 halo tile ----
#pragma unroll
    for (int it = 0; it < NITER; ++it) {
        const int i = tid + it * 256;
        if (i < NCHUNK) {
            const int r  = i / NC4;
            const int c4 = i - r * NC4;
            const int gy = gy0 + r;
            const int gx = gx0 + c4 * 4;
            float4 v = make_float4(0.f, 0.f, 0.f, 0.f);
            if (gy < IH && gx + 3 < IW) {
                v = *reinterpret_cast<const float4*>(x + (size_t)gy * IW + gx);
            }
            *reinterpret_cast<float4*>(&tile[r * LDS_W + FSWZ(r) + c4 * 4]) = v;
        }
    }
    __syncthreads();

    const int tx = tid & (TX - 1);
    const int ty = tid >> 4;
    const int lx = tx * TN;
    const int ly = ty * TM;

    float acc[TM][TN] = {};

    // Rotating weight rows (VGPR): at most 4 rows (44 floats) live at once —
    // row kh is loaded at iteration r=kh and last used at r=kh+3.
    float wr[4][KW];

    // Opaque zero. Injected into every load address inside the r-loop and
    // re-written each iteration with a dependency on this iteration's last
    // accumulator: the NEXT iteration's loads cannot be hoisted above THIS
    // iteration's FMAs. This caps the scheduler's live set (~95 regs) —
    // rounds 0-2 showed it otherwise hoists all 196 xv loads -> 256 VGPR.
    int guard = 0;

#pragma unroll
    for (int r = 0; r < TM + KH - 1; ++r) {     // 14 iterations
        if (r < KH) {
            const float* wrow = w + r * KW + guard;
#pragma unroll
            for (int kw = 0; kw < KW; ++kw) wr[r & 3][kw] = wrow[kw];
        }

        // 14 floats of input row (ly + r): 3x ds_read_b128 + 1x ds_read_b64.
        float xv[TN + KW - 1];                   // 14
        {
            const int row = ly + r;
            const float* src = &tile[row * LDS_W + FSWZ(row) + lx + guard];
            float4 a = *reinterpret_cast<const float4*>(src);
            float4 b = *reinterpret_cast<const float4*>(src + 4);
            float4 c = *reinterpret_cast<const float4*>(src + 8);
            float2 d = *reinterpret_cast<const float2*>(src + 12);
            xv[0]=a.x;  xv[1]=a.y;  xv[2]=a.z;  xv[3]=a.w;
            xv[4]=b.x;  xv[5]=b.y;  xv[6]=b.z;  xv[7]=b.w;
            xv[8]=c.x;  xv[9]=c.y;  xv[10]=c.z; xv[11]=c.w;
            xv[12]=d.x; xv[13]=d.y;
        }

#pragma unroll
        for (int ry = 0; ry < TM; ++ry) {
            const int kh = r - ry;               // compile-time
            if (kh >= 0 && kh < KH) {
#pragma unroll
                for (int kw = 0; kw < KW; ++kw) {
                    const float wv = wr[kh & 3][kw];
#pragma unroll
                    for (int rx = 0; rx < TN; ++rx) {
                        acc[ry][rx] = fmaf(xv[kw + rx], wv, acc[ry][rx]);
                    }
                }
            }
        }

        // False dep: guard (still 0) now "depends on" this iteration's acc.
        asm volatile("" : "+v"(guard) : "v"(acc[TM - 1][TN - 1]));
        // And keep this iteration's FMAs from drifting below the next
        // iteration's loads (bounds xv liveness from the other side).
        __builtin_amdgcn_sched_barrier(0);
    }

    // ---- Write back ----
    const float bv = bias[0];
    const int ox = gx0 + lx;
#pragma unroll
    for (int ry = 0; ry < TM; ++ry) {
        const int oy = gy0 + ly + ry;
        if (oy < OH) {
            const size_t base = (size_t)oy * OW + ox;
            if (ox + TN - 1 < OW) {
                float2 p0 = make_float2(acc[ry][0] + bv, acc[ry][1] + bv);
                float2 p1 = make_float2(acc[ry][2] + bv, acc[ry][3] + bv);
                *reinterpret_cast<float2*>(out + base)     = p0;
                *reinterpret_cast<float2*>(out + base + 2) = p1;
            } else {
#pragma unroll
                for (int rx = 0; rx < TN; ++rx) {
                    if (ox + rx < OW) out[base + rx] = acc[ry][rx] + bv;
                }
            }
        }
    }
}

extern "C" void kernel_launch(void* const* d_in, const int* in_sizes, int n_in,
                              void* d_out, int out_size, void* d_ws, size_t ws_size,
                              hipStream_t stream) {
    const float* x    = (const float*)d_in[0];
    const float* w    = (const float*)d_in[1];
    const float* bias = (const float*)d_in[2];
    float* out        = (float*)d_out;

    dim3 grid((OW + BN - 1) / BN, (OH + BM - 1) / BM);  // 64 x 64
    dim3 block(TX * TY);                                 // 256
    conv2d_f32_tile<<<grid, block, 0, stream>>>(x, w, bias, out);
}

// Round 6
// 143.320 us; speedup vs baseline: 15.1226x; 15.1226x over previous
//
#include <hip/hip_runtime.h>

// Problem constants
#define IH 4096
#define IW 4096
#define KH 11
#define KW 11
#define OH (IH - KH + 1)   // 4086
#define OW (IW - KW + 1)   // 4086

// Tiling
#define BM 64              // output tile rows per block
#define BN 64              // output tile cols per block
#define TM 4               // outputs per thread (rows)
#define TN 4               // outputs per thread (cols)
#define TX 16              // threads in x
#define TY 16              // threads in y
#define LDS_H (BM + KH - 1)        // 74 input rows
#define LDS_W 84                   // row stride (floats); 76 data + 8 swizzle slack
#define NC4   19                   // float4 chunks per row (76 floats >= 74)
#define NCHUNK (LDS_H * NC4)       // 1406
#define NITER  ((NCHUNK + 255) / 256) // 6 staging iterations

// Bank-conflict swizzle. Within one wave the 4 ty-groups read rows r, r+4,
// r+8, r+12. row*84 mod 32 = row*20 mod 32 gives offsets {0,16,0,16} for the
// 4 groups; FSWZ adds {0,8} by row>>3 -> {0,16,8,24}: distinct quadrants.
// Multiple of 8 floats (32 B) keeps 16B alignment; 76+8 <= 84 fits stride.
#define FSWZ(row) ((((row) >> 3) & 1) * 8)

// Wave-uniform -> SGPR (v_fma_f32 may take one SGPR operand).
__device__ __forceinline__ float rfl(float v) {
    return __int_as_float(__builtin_amdgcn_readfirstlane(__float_as_int(v)));
}

__global__ __launch_bounds__(256)
void conv2d_f32_tile(const float* __restrict__ x,
                     const float* __restrict__ w,
                     const float* __restrict__ bias,
                     float* __restrict__ out) {
    __shared__ float tile[LDS_H * LDS_W];   // 74*84*4 = 24864 B

    const int tid = threadIdx.x;
    const int gx0 = blockIdx.x * BN;
    const int gy0 = blockIdx.y * BM;

    // ---- Stage 74x74 halo tile ----
#pragma unroll
    for (int it = 0; it < NITER; ++it) {
        const int i = tid + it * 256;
        if (i < NCHUNK) {
            const int r  = i / NC4;
            const int c4 = i - r * NC4;
            const int gy = gy0 + r;
            const int gx = gx0 + c4 * 4;
            float4 v = make_float4(0.f, 0.f, 0.f, 0.f);
            if (gy < IH && gx + 3 < IW) {
                v = *reinterpret_cast<const float4*>(x + (size_t)gy * IW + gx);
            }
            *reinterpret_cast<float4*>(&tile[r * LDS_W + FSWZ(r) + c4 * 4]) = v;
        }
    }
    __syncthreads();

    const int tx = tid & (TX - 1);
    const int ty = tid >> 4;
    const int lx = tx * TN;
    const int ly = ty * TM;

    float acc[TM][TN] = {};

    // RUNTIME loop over weight rows — 11 small iterations. The loop boundary
    // bounds the scheduler's live set by construction (rounds 0-5: any fully
    // unrolled 14-row body ballooned to >200 live regs; caps/hints only
    // converted that into scratch spills).
#pragma unroll 1
    for (int kh = 0; kh < KH; ++kh) {
        // 11 wave-uniform weights for this kernel row -> SGPRs.
        float wk[KW];
#pragma unroll
        for (int kw = 0; kw < KW; ++kw) wk[kw] = rfl(w[kh * KW + kw]);

#pragma unroll
        for (int ry = 0; ry < TM; ++ry) {
            const int row = ly + ry + kh;
            // 14 floats of input row: 3x ds_read_b128 + 1x ds_read_b64.
            float xv[TN + KW - 1];
            {
                const float* src = &tile[row * LDS_W + FSWZ(row) + lx];
                float4 a = *reinterpret_cast<const float4*>(src);
                float4 b = *reinterpret_cast<const float4*>(src + 4);
                float4 c = *reinterpret_cast<const float4*>(src + 8);
                float2 d = *reinterpret_cast<const float2*>(src + 12);
                xv[0]=a.x;  xv[1]=a.y;  xv[2]=a.z;  xv[3]=a.w;
                xv[4]=b.x;  xv[5]=b.y;  xv[6]=b.z;  xv[7]=b.w;
                xv[8]=c.x;  xv[9]=c.y;  xv[10]=c.z; xv[11]=c.w;
                xv[12]=d.x; xv[13]=d.y;
            }
#pragma unroll
            for (int kw = 0; kw < KW; ++kw) {
                const float wv = wk[kw];           // SGPR operand
#pragma unroll
                for (int rx = 0; rx < TN; ++rx) {
                    acc[ry][rx] = fmaf(xv[kw + rx], wv, acc[ry][rx]);
                }
            }
        }
    }

    // ---- Write back ----
    const float bv = bias[0];
    const int ox = gx0 + lx;
#pragma unroll
    for (int ry = 0; ry < TM; ++ry) {
        const int oy = gy0 + ly + ry;
        if (oy < OH) {
            const size_t base = (size_t)oy * OW + ox;
            if (ox + TN - 1 < OW) {
                float2 p0 = make_float2(acc[ry][0] + bv, acc[ry][1] + bv);
                float2 p1 = make_float2(acc[ry][2] + bv, acc[ry][3] + bv);
                *reinterpret_cast<float2*>(out + base)     = p0;
                *reinterpret_cast<float2*>(out + base + 2) = p1;
            } else {
#pragma unroll
                for (int rx = 0; rx < TN; ++rx) {
                    if (ox + rx < OW) out[base + rx] = acc[ry][rx] + bv;
                }
            }
        }
    }
}

extern "C" void kernel_launch(void* const* d_in, const int* in_sizes, int n_in,
                              void* d_out, int out_size, void* d_ws, size_t ws_size,
                              hipStream_t stream) {
    const float* x    = (const float*)d_in[0];
    const float* w    = (const float*)d_in[1];
    const float* bias = (const float*)d_in[2];
    float* out        = (float*)d_out;

    dim3 grid((OW + BN - 1) / BN, (OH + BM - 1) / BM);  // 64 x 64
    dim3 block(TX * TY);                                 // 256
    conv2d_f32_tile<<<grid, block, 0, stream>>>(x, w, bias, out);
}

// Round 8
// 114.158 us; speedup vs baseline: 18.9857x; 1.2555x over previous
//
#include <hip/hip_runtime.h>

// Problem constants
#define IH 4096
#define IW 4096
#define KH 11
#define KW 11
#define OH (IH - KH + 1)   // 4086
#define OW (IW - KW + 1)   // 4086

// Tiling
#define BM 64              // output tile rows per block
#define BN 64              // output tile cols per block
#define TM 4               // outputs per thread (rows)
#define TN 4               // outputs per thread (cols)
#define TX 16              // threads in x
#define TY 16              // threads in y
#define LDS_H (BM + KH - 1)        // 74 input rows
#define LDS_W 76                   // row stride (floats): 74 data + 2 swizzle
#define NC    19                   // chunks per row: 18 float4 + 1 float2 (=74 floats)
#define NCHUNK (LDS_H * NC)        // 1406
#define NITER  ((NCHUNK + 255) / 256) // 6 staging iterations

// Bank-conflict fix (phase model): LDS serves 32 lanes x 4B per cycle; a
// multi-word read phase holds word j of lanes 0-31 = two 16-lane ty-groups.
// A ty-group covers banks {(base+j) mod 4 + 4k} each twice; any multiple-of-
// 4-float base has residue 0 -> both groups share one 8-bank set -> 4-way.
// (Measured: stride 76 / 84 / FSWZ(x8) all identical ~18 extra cyc/read.)
// Fix: 2-float (8B) per-row offset alternating on (row>>2)&1 — the two
// ty-groups in a phase read rows differing by 4, so their residues differ
// by 2 -> disjoint bank sets. Rows must be read as ds_read_b64 (8B-aligned).
#define OF(row) ((((row) >> 2) & 1) * 2)

// Wave-uniform -> SGPR (v_fma_f32 may take one SGPR operand).
__device__ __forceinline__ float rfl(float v) {
    return __int_as_float(__builtin_amdgcn_readfirstlane(__float_as_int(v)));
}

__global__ __launch_bounds__(256)
void conv2d_f32_tile(const float* __restrict__ x,
                     const float* __restrict__ w,
                     const float* __restrict__ bias,
                     float* __restrict__ out) {
    __shared__ float tile[LDS_H * LDS_W + 2];

    const int tid = threadIdx.x;
    const int gx0 = blockIdx.x * BN;
    const int gy0 = blockIdx.y * BM;

    // ---- Stage 74x74 halo tile ----
    // Exactly 74 floats per row: chunks 0..17 write float4 (as 2x b64 to
    // respect the 8B swizzle alignment), chunk 18 writes float2 (cols 72,73).
    // Round-7 bug: writing 76 floats/row overflowed 2 floats into the next
    // row's slot at OF 2->0 transitions -> write race -> corruption.
#pragma unroll
    for (int it = 0; it < NITER; ++it) {
        const int i = tid + it * 256;
        if (i < NCHUNK) {
            const int r  = i / NC;
            const int c4 = i - r * NC;
            const int gy = gy0 + r;
            const int gx = gx0 + c4 * 4;
            float4 v = make_float4(0.f, 0.f, 0.f, 0.f);
            if (gy < IH && gx + 3 < IW) {
                v = *reinterpret_cast<const float4*>(x + (size_t)gy * IW + gx);
            }
            float* dst = &tile[r * LDS_W + OF(r) + c4 * 4];   // 8B aligned
            *reinterpret_cast<float2*>(dst) = make_float2(v.x, v.y);
            if (c4 < NC - 1) {
                *reinterpret_cast<float2*>(dst + 2) = make_float2(v.z, v.w);
            }
        }
    }
    __syncthreads();

    const int tx = tid & (TX - 1);
    const int ty = tid >> 4;
    const int lx = tx * TN;
    const int ly = ty * TM;

    float acc[TM][TN] = {};

    // RUNTIME loop over weight rows — 11 small iterations; the loop boundary
    // bounds the scheduler's live set (rounds 0-5: any fully-unrolled 14-row
    // body ballooned to >200 live regs; caps only converted that to spills).
#pragma unroll 1
    for (int kh = 0; kh < KH; ++kh) {
        // 11 wave-uniform weights for this kernel row -> SGPRs.
        float wk[KW];
#pragma unroll
        for (int kw = 0; kw < KW; ++kw) wk[kw] = rfl(w[kh * KW + kw]);

#pragma unroll
        for (int ry = 0; ry < TM; ++ry) {
            const int row = ly + ry + kh;
            // 14 floats of input row: 7x ds_read_b64 (8B-aligned; the 2-float
            // swizzle makes b128 merging impossible to prove -> stays b64).
            float xv[TN + KW - 1];
            {
                const float* src = &tile[row * LDS_W + OF(row) + lx];
                float2 p0 = *reinterpret_cast<const float2*>(src);
                float2 p1 = *reinterpret_cast<const float2*>(src + 2);
                float2 p2 = *reinterpret_cast<const float2*>(src + 4);
                float2 p3 = *reinterpret_cast<const float2*>(src + 6);
                float2 p4 = *reinterpret_cast<const float2*>(src + 8);
                float2 p5 = *reinterpret_cast<const float2*>(src + 10);
                float2 p6 = *reinterpret_cast<const float2*>(src + 12);
                xv[0]=p0.x;  xv[1]=p0.y;  xv[2]=p1.x;  xv[3]=p1.y;
                xv[4]=p2.x;  xv[5]=p2.y;  xv[6]=p3.x;  xv[7]=p3.y;
                xv[8]=p4.x;  xv[9]=p4.y;  xv[10]=p5.x; xv[11]=p5.y;
                xv[12]=p6.x; xv[13]=p6.y;
            }
#pragma unroll
            for (int kw = 0; kw < KW; ++kw) {
                const float wv = wk[kw];           // SGPR operand
#pragma unroll
                for (int rx = 0; rx < TN; ++rx) {
                    acc[ry][rx] = fmaf(xv[kw + rx], wv, acc[ry][rx]);
                }
            }
        }
    }

    // ---- Write back ----
    const float bv = bias[0];
    const int ox = gx0 + lx;
#pragma unroll
    for (int ry = 0; ry < TM; ++ry) {
        const int oy = gy0 + ly + ry;
        if (oy < OH) {
            const size_t base = (size_t)oy * OW + ox;
            if (ox + TN - 1 < OW) {
                float2 p0 = make_float2(acc[ry][0] + bv, acc[ry][1] + bv);
                float2 p1 = make_float2(acc[ry][2] + bv, acc[ry][3] + bv);
                *reinterpret_cast<float2*>(out + base)     = p0;
                *reinterpret_cast<float2*>(out + base + 2) = p1;
            } else {
#pragma unroll
                for (int rx = 0; rx < TN; ++rx) {
                    if (ox + rx < OW) out[base + rx] = acc[ry][rx] + bv;
                }
            }
        }
    }
}

extern "C" void kernel_launch(void* const* d_in, const int* in_sizes, int n_in,
                              void* d_out, int out_size, void* d_ws, size_t ws_size,
                              hipStream_t stream) {
    const float* x    = (const float*)d_in[0];
    const float* w    = (const float*)d_in[1];
    const float* bias = (const float*)d_in[2];
    float* out        = (float*)d_out;

    dim3 grid((OW + BN - 1) / BN, (OH + BM - 1) / BM);  // 64 x 64
    dim3 block(TX * TY);                                 // 256
    conv2d_f32_tile<<<grid, block, 0, stream>>>(x, w, bias, out);
}

// Round 9
// 71.080 us; speedup vs baseline: 30.4921x; 1.6061x over previous
//
#include <hip/hip_runtime.h>

// Problem constants
#define IH 4096
#define IW 4096
#define KH 11
#define KW 11
#define OH (IH - KH + 1)   // 4086
#define OW (IW - KW + 1)   // 4086

// Tiling
#define BM 64              // output tile rows per block
#define BN 64              // output tile cols per block
#define TM 4               // outputs per thread (rows)
#define TN 4               // outputs per thread (cols)
#define TX 16              // threads in x
#define TY 16              // threads in y
#define LDS_H (BM + KH - 1)        // 74 input rows
#define LDS_W 76                   // row stride (floats): 74 data + 2 swizzle
#define NC    19                   // chunks/row: 18 float4 + 1 float2 (=74 floats)
#define NCHUNK (LDS_H * NC)        // 1406
#define NITER  ((NCHUNK + 255) / 256) // 6 staging iterations

// 8B-per-row swizzle (round 8): rows 4 apart get mod-4 bank residues {0,2} —
// halves the b64 word-phase conflict. Full fix impossible at 8B alignment;
// this round attacks READ COUNT instead (rolling registers, 3.1x fewer).
#define OF(row) ((((row) >> 2) & 1) * 2)

// Wave-uniform -> SGPR (v_fma_f32 may take one SGPR operand).
__device__ __forceinline__ float rfl(float v) {
    return __int_as_float(__builtin_amdgcn_readfirstlane(__float_as_int(v)));
}

__global__ __launch_bounds__(256)
void conv2d_f32_tile(const float* __restrict__ x,
                     const float* __restrict__ w,
                     const float* __restrict__ bias,
                     float* __restrict__ out) {
    __shared__ float tile[LDS_H * LDS_W + 2];

    const int tid = threadIdx.x;
    const int gx0 = blockIdx.x * BN;
    const int gy0 = blockIdx.y * BM;

    // ---- Stage 74x74 halo tile (exactly 74 floats/row; round-7 overflow
    // bug fixed in round 8 — keep identical) ----
#pragma unroll
    for (int it = 0; it < NITER; ++it) {
        const int i = tid + it * 256;
        if (i < NCHUNK) {
            const int r  = i / NC;
            const int c4 = i - r * NC;
            const int gy = gy0 + r;
            const int gx = gx0 + c4 * 4;
            float4 v = make_float4(0.f, 0.f, 0.f, 0.f);
            if (gy < IH && gx + 3 < IW) {
                v = *reinterpret_cast<const float4*>(x + (size_t)gy * IW + gx);
            }
            float* dst = &tile[r * LDS_W + OF(r) + c4 * 4];   // 8B aligned
            *reinterpret_cast<float2*>(dst) = make_float2(v.x, v.y);
            if (c4 < NC - 1) {
                *reinterpret_cast<float2*>(dst + 2) = make_float2(v.z, v.w);
            }
        }
    }
    __syncthreads();

    const int tx = tid & (TX - 1);
    const int ty = tid >> 4;
    const int lx = tx * TN;
    const int ly = ty * TM;

    float acc[TM][TN] = {};

    // Rolling row registers: 4 rows x 14 floats live; iteration kh loads ONE
    // new row (kh+3) and reuses 3. Slot index (kh+ry)&3 is compile-time via
    // the macro-literal U. Total LDS row-reads/thread: 14 (vs 44 in round 8).
    float xv[4][14];

#define LOADROW(S, RR) do {                                                  \
        const int row_ = ly + (RR);                                          \
        const float* src_ = &tile[row_ * LDS_W + OF(row_) + lx];             \
        float2 q0 = *reinterpret_cast<const float2*>(src_);                  \
        float2 q1 = *reinterpret_cast<const float2*>(src_ + 2);              \
        float2 q2 = *reinterpret_cast<const float2*>(src_ + 4);              \
        float2 q3 = *reinterpret_cast<const float2*>(src_ + 6);              \
        float2 q4 = *reinterpret_cast<const float2*>(src_ + 8);              \
        float2 q5 = *reinterpret_cast<const float2*>(src_ + 10);             \
        float2 q6 = *reinterpret_cast<const float2*>(src_ + 12);             \
        xv[(S)][0]=q0.x;  xv[(S)][1]=q0.y;  xv[(S)][2]=q1.x;  xv[(S)][3]=q1.y; \
        xv[(S)][4]=q2.x;  xv[(S)][5]=q2.y;  xv[(S)][6]=q3.x;  xv[(S)][7]=q3.y; \
        xv[(S)][8]=q4.x;  xv[(S)][9]=q4.y;  xv[(S)][10]=q5.x; xv[(S)][11]=q5.y; \
        xv[(S)][12]=q6.x; xv[(S)][13]=q6.y;                                  \
    } while (0)

    // One kh step. U = kh&3 (literal). Loads row kh+3 into slot (U+3)&3
    // (overwrites row kh-1, last used in the previous step), then 44 FMAs.
#define STEP(U, KHV) do {                                                    \
        LOADROW(((U) + 3) & 3, (KHV) + 3);                                   \
        float wk[KW];                                                        \
        _Pragma("unroll")                                                    \
        for (int kw = 0; kw < KW; ++kw) wk[kw] = rfl(w[(KHV) * KW + kw]);    \
        _Pragma("unroll")                                                    \
        for (int ry = 0; ry < TM; ++ry) {                                    \
            const float* xr = xv[((U) + ry) & 3];                            \
            _Pragma("unroll")                                                \
            for (int kw = 0; kw < KW; ++kw) {                                \
                const float wv = wk[kw];                                     \
                _Pragma("unroll")                                            \
                for (int rx = 0; rx < TN; ++rx) {                            \
                    acc[ry][rx] = fmaf(xr[kw + rx], wv, acc[ry][rx]);        \
                }                                                            \
            }                                                                \
        }                                                                    \
    } while (0)

    // Prologue: rows 0,1,2 into slots 0,1,2.
    LOADROW(0, 0);
    LOADROW(1, 1);
    LOADROW(2, 2);

    // kh = 0..7 as 2 runtime iterations of an unroll-4 body; the runtime
    // loop boundary bounds the scheduler's live set (rounds 0-5 lesson).
#pragma unroll 1
    for (int t = 0; t < 2; ++t) {
        const int kh0 = 4 * t;
        STEP(0, kh0 + 0);
        STEP(1, kh0 + 1);
        STEP(2, kh0 + 2);
        STEP(3, kh0 + 3);
    }
    // Tail kh = 8,9,10 (kh&3 = 0,1,2).
    STEP(0, 8);
    STEP(1, 9);
    STEP(2, 10);

#undef STEP
#undef LOADROW

    // ---- Write back ----
    const float bv = bias[0];
    const int ox = gx0 + lx;
#pragma unroll
    for (int ry = 0; ry < TM; ++ry) {
        const int oy = gy0 + ly + ry;
        if (oy < OH) {
            const size_t base = (size_t)oy * OW + ox;
            if (ox + TN - 1 < OW) {
                float2 p0 = make_float2(acc[ry][0] + bv, acc[ry][1] + bv);
                float2 p1 = make_float2(acc[ry][2] + bv, acc[ry][3] + bv);
                *reinterpret_cast<float2*>(out + base)     = p0;
                *reinterpret_cast<float2*>(out + base + 2) = p1;
            } else {
#pragma unroll
                for (int rx = 0; rx < TN; ++rx) {
                    if (ox + rx < OW) out[base + rx] = acc[ry][rx] + bv;
                }
            }
        }
    }
}

extern "C" void kernel_launch(void* const* d_in, const int* in_sizes, int n_in,
                              void* d_out, int out_size, void* d_ws, size_t ws_size,
                              hipStream_t stream) {
    const float* x    = (const float*)d_in[0];
    const float* w    = (const float*)d_in[1];
    const float* bias = (const float*)d_in[2];
    float* out        = (float*)d_out;

    dim3 grid((OW + BN - 1) / BN, (OH + BM - 1) / BM);  // 64 x 64
    dim3 block(TX * TY);                                 // 256
    conv2d_f32_tile<<<grid, block, 0, stream>>>(x, w, bias, out);
}